// Round 1
// 9582.910 us; speedup vs baseline: 1.2626x; 1.2626x over previous
//
#include <hip/hip_runtime.h>

// RnnGenerator: C=2048, 4-layer ReLU RNN, 512 autoregressive steps = 2048
// strictly serial GEMV stages + 3-layer MLP LengthProducer.
// Round-6: flag-gated pull replaces per-element tag polling.
//  - Round-5 diagnosis (Little's law): 131072 threads x 8 polled 8B
//    agent-scope loads = ~1M in-flight requests over ~512 hot lines ->
//    ~5.9us queue latency per round == the 5.9us stage time. Congestion,
//    not visibility latency, was the floor.
//  - Fix: per-block monotone stage counter done[256]. Producer's existing
//    end-of-stage __syncthreads() drains vmcnt(0) (hipcc emits it before
//    s_barrier), so the agent-scope write-through data stores are globally
//    visible before thread0 fire-and-forgets done[b]=g. One wave per block
//    polls done[] with 64 dwordx4 sc1 loads -> 16K req/round (64x fewer).
//  - Data is now untagged fp32, pulled ONCE per stage per thread as a
//    single global_load_dwordx4 sc1 (device scope: bypass L1 + per-XCD L2,
//    served at Infinity Cache = the stores' coherence point).
//  - hidb (B operand) was published >=4 stages ago -> loaded before the
//    flag poll, fully overlapped. Per-block rotated slice index staggers
//    the 256-way broadcast of the same 8KB across lines.
//  - Weight residency unchanged: layers 0-2 rows in VGPRs, layer 3 in LDS
//    (128 KB dyn), 16 KB static staging. 256 WGs x 512 thr, 1 WG/CU.
// fp32 everywhere: states binarize to exactly {0,1} via h/(h+1e-12);
// bf16 would flip near-zero pre-activation signs (trajectory is chaotic).

#define C      2048
#define NB     256
#define NT     512
#define STEPS  512

typedef unsigned long long u64;
typedef unsigned int u32;

// ws layout:
//   u64   lp[3][C]     tagged LP dataflow words (unchanged scheme, 48 KB)
//   float f[13*C]:     inp[2][C] | hidb[2][4][C] | hraw[3][C]   (104 KB)
//   u32   done[NB]     per-block completed-stage counters        (1 KB)
#define F_INP   0
#define F_HIDB  (2*C)
#define F_HRAW  (10*C)

__device__ __forceinline__ float wred(float v) {
#pragma unroll
  for (int off = 32; off > 0; off >>= 1) v += __shfl_down(v, off, 64);
  return v;
}

// ---- tagged u64 helpers (LengthProducer only) ----
__device__ __forceinline__ u64 pack(float val, int tag) {
  return ((u64)(unsigned)tag << 32) | (u64)__float_as_uint(val);
}
__device__ __forceinline__ void pub64(u64* p, float val, int tag) {
  __hip_atomic_store(p, pack(val, tag), __ATOMIC_RELAXED, __HIP_MEMORY_SCOPE_AGENT);
}
__device__ __forceinline__ u64 peek(u64* p) {
  return __hip_atomic_load(p, __ATOMIC_RELAXED, __HIP_MEMORY_SCOPE_AGENT);
}
__device__ __forceinline__ float val_of(u64 v) { return __uint_as_float((unsigned)v); }
__device__ __forceinline__ int   tag_of(u64 v) { return (int)(v >> 32); }

// ---- device-scope (agent) coherent 16B loads: bypass L1 + per-XCD L2,
//      served at Infinity Cache. Load+wait fused in one asm so the result
//      is genuinely ready when the asm "returns" (no rule-#18 hazard). ----
__device__ __forceinline__ float4 ldx4_dev(const float* p) {
  float4 r;
  asm volatile("global_load_dwordx4 %0, %1, off sc1\n\t"
               "s_waitcnt vmcnt(0)"
               : "=v"(r) : "v"(p) : "memory");
  return r;
}
__device__ __forceinline__ uint4 ldu4_dev(const u32* p) {
  uint4 r;
  asm volatile("global_load_dwordx4 %0, %1, off sc1\n\t"
               "s_waitcnt vmcnt(0)"
               : "=v"(r) : "v"(p) : "memory");
  return r;
}
__device__ __forceinline__ void stf_dev(float* p, float v) {
  __hip_atomic_store(p, v, __ATOMIC_RELAXED, __HIP_MEMORY_SCOPE_AGENT);
}

// LP poll: tagged per-element (3 stages only, off the 12ms-scale path)
__device__ __forceinline__ void poll1(u64* __restrict__ A, int tagA,
                                      float* __restrict__ sa, int tid) {
  u64* a = A + 4 * tid;
  u64 va0, va1, va2, va3;
  for (;;) {
    va0 = peek(a + 0); va1 = peek(a + 1); va2 = peek(a + 2); va3 = peek(a + 3);
    bool ok = (tag_of(va0) == tagA) & (tag_of(va1) == tagA)
            & (tag_of(va2) == tagA) & (tag_of(va3) == tagA);
    if (ok) break;
    __builtin_amdgcn_s_sleep(2);
  }
  float4 fa = { val_of(va0), val_of(va1), val_of(va2), val_of(va3) };
  ((float4*)sa)[tid] = fa;
}

__global__ void init_kernel(const float* __restrict__ x, u64* __restrict__ ws) {
  float* f    = (float*)(ws + 3 * C);
  u32*   done = (u32*)(f + 13 * C);
  int i = blockIdx.x * blockDim.x + threadIdx.x;
  if (i < C) {
    f[F_INP + i]          = 0.f;    // inp parity 0 (t=0 input) = zeros
    f[F_HIDB + 0 * C + i] = x[i];   // hid layer0 (t=-1) = x (raw floats!)
    f[F_HIDB + 1 * C + i] = 0.f;
    f[F_HIDB + 2 * C + i] = 0.f;
    f[F_HIDB + 3 * C + i] = 0.f;
  }
  if (i < NB) done[i] = 0;
}

__global__ __launch_bounds__(NT, 2) void rnn_persist(
    const float* __restrict__ x,
    const float* __restrict__ lp_w,  const float* __restrict__ lp_b,
    const float* __restrict__ lp_wout, const float* __restrict__ lp_bout,
    const float* __restrict__ w_ih,  const float* __restrict__ b_ih,
    const float* __restrict__ w_hh,  const float* __restrict__ b_hh,
    float* __restrict__ out, u64* __restrict__ ws)
{
  extern __shared__ float4 w3[];            // 8 waves x 2 mats x 512 f4 = 128 KB
  __shared__ __align__(16) float sh_a[C];   // 8 KB staged input vector
  __shared__ __align__(16) float sh_b[C];   // 8 KB staged hidden vector

  u64*   lp   = ws;                         // 3*C tagged u64
  float* f    = (float*)(ws + 3 * C);
  float* inp  = f + F_INP;
  float* hidb = f + F_HIDB;
  float* hraw = f + F_HRAW;
  u32*   done = (u32*)(f + 13 * C);

  const int tid  = threadIdx.x;
  const int lane = tid & 63;
  const int wid  = tid >> 6;
  const int j    = blockIdx.x * 8 + wid;    // unit owned by this wave

  // ---------------- prime: layers 0-2 rows -> regs, layer 3 -> LDS --------
  const float4* WI = (const float4*)w_ih;
  const float4* WH = (const float4*)w_hh;
  float4 wir[3][8], whr[3][8];
#pragma unroll
  for (int l = 0; l < 3; ++l) {
    const size_t bi = (size_t)(l * C + j) * 512;
#pragma unroll
    for (int r = 0; r < 8; ++r) {
      wir[l][r] = WI[bi + r * 64 + lane];
      whr[l][r] = WH[bi + r * 64 + lane];
    }
  }
  {
    const size_t b3 = (size_t)(3 * C + j) * 512;
#pragma unroll
    for (int r = 0; r < 8; ++r) {
      w3[(wid * 2 + 0) * 512 + r * 64 + lane] = WI[b3 + r * 64 + lane];
      w3[(wid * 2 + 1) * 512 + r * 64 + lane] = WH[b3 + r * 64 + lane];
    }
  }
  float bias[4];
#pragma unroll
  for (int l = 0; l < 4; ++l) bias[l] = b_ih[l * C + j] + b_hh[l * C + j];
  __syncthreads();

  // ---------------- LengthProducer (tagged dataflow, unchanged) ----------
  for (int s = 0; s < 3; ++s) {
    if (s == 0) ((float4*)sh_a)[tid] = ((const float4*)x)[tid];
    else        poll1(lp + (size_t)(s - 1) * C, s, sh_a, tid);
    __syncthreads();
    const float4* Wr  = (const float4*)(lp_w + ((size_t)s * C + j) * C);
    const float4* sa4 = (const float4*)sh_a;
    float a0 = 0, a1 = 0, a2 = 0, a3 = 0;
#pragma unroll
    for (int r = 0; r < 8; ++r) {
      float4 w = Wr[r * 64 + lane]; float4 h = sa4[r * 64 + lane];
      a0 = fmaf(w.x, h.x, a0); a1 = fmaf(w.y, h.y, a1);
      a2 = fmaf(w.z, h.z, a2); a3 = fmaf(w.w, h.w, a3);
    }
    float acc = wred((a0 + a1) + (a2 + a3));
    if (lane == 0) {
      float v = acc + lp_b[s * C + j];
      pub64(&lp[(size_t)s * C + j], (v >= 0.f) ? v : 0.2f * v, s + 1);
    }
    __syncthreads();   // sh_a reuse protection
  }

  // LP head: block 0 wave 0 polls lp[2] (tag 3), batched 8-wide.
  if (blockIdx.x == 0 && wid == 0) {
    float p = 0.f;
#pragma unroll
    for (int g = 0; g < 4; ++g) {
      u64 v[8];
      for (;;) {
        bool ok = true;
#pragma unroll
        for (int r = 0; r < 8; ++r)
          v[r] = peek(&lp[2 * C + (g * 8 + r) * 64 + lane]);
#pragma unroll
        for (int r = 0; r < 8; ++r) ok &= (tag_of(v[r]) == 3);
        if (ok) break;
        __builtin_amdgcn_s_sleep(2);
      }
#pragma unroll
      for (int r = 0; r < 8; ++r)
        p = fmaf(lp_wout[(g * 8 + r) * 64 + lane], val_of(v[r]), p);
    }
    p = wred(p);
    if (lane == 0) {
      float l = fabsf(p + lp_bout[0]);
      out[(size_t)STEPS * C] = fminf(l, 0.9999f);
    }
  }

  // ---------------- 512 steps x 4 layers, flag-gated pull -----------------
  // Per-block rotated slice: staggers the 256-way broadcast of the same
  // 8 KB vector across cache lines (blocks b, b+2 start one line apart).
  const int q = (tid + 2 * blockIdx.x) & (NT - 1);

  for (int t = 0; t < STEPS; ++t) {
    const int p = t & 1;
#pragma unroll
    for (int l = 0; l < 4; ++l) {
      const u32 tgt = (u32)(4 * t + l);    // stage index we depend on

      // B (hidden state) was published at stage tgt-3 and gated visible by
      // the previous stage's poll (done >= tgt-1 observed) -> load now,
      // fully overlapped with the A-readiness poll below.
      const float* B = hidb + (size_t)(p * 4 + l) * C;
      float4 vb = ldx4_dev(B + 4 * q);
      ((float4*)sh_b)[q] = vb;

      // A readiness: wave 0 polls the 256 per-block stage counters.
      // 64 lanes x 1 dwordx4 = 64 requests per block per round.
      if (tid < 64) {
        for (;;) {
          uint4 v = ldu4_dev(done + 4 * tid);
          bool ok = (v.x >= tgt) & (v.y >= tgt) & (v.z >= tgt) & (v.w >= tgt);
          if (__all(ok)) break;
          __builtin_amdgcn_s_sleep(2);
        }
      }
      __syncthreads();

      // A pull: one coherent 16B load per thread, once.
      const float* A = (l == 0) ? (inp + (size_t)p * C)
                                : (hraw + (size_t)(l - 1) * C);
      float4 va = ldx4_dev(A + 4 * q);
      ((float4*)sh_a)[q] = va;
      __syncthreads();

      const float4* sa4 = (const float4*)sh_a;
      const float4* sb4 = (const float4*)sh_b;
      float a0 = 0, a1 = 0, a2 = 0, a3 = 0;
      if (l < 3) {
#pragma unroll
        for (int r = 0; r < 8; ++r) {
          float4 h = sa4[r * 64 + lane]; float4 w = wir[l][r];
          a0 = fmaf(w.x, h.x, a0); a1 = fmaf(w.y, h.y, a1);
          a2 = fmaf(w.z, h.z, a2); a3 = fmaf(w.w, h.w, a3);
          float4 g = sb4[r * 64 + lane]; float4 v = whr[l][r];
          a0 = fmaf(v.x, g.x, a0); a1 = fmaf(v.y, g.y, a1);
          a2 = fmaf(v.z, g.z, a2); a3 = fmaf(v.w, g.w, a3);
        }
      } else {
#pragma unroll
        for (int r = 0; r < 8; ++r) {
          float4 h = sa4[r * 64 + lane]; float4 w = w3[(wid * 2 + 0) * 512 + r * 64 + lane];
          a0 = fmaf(w.x, h.x, a0); a1 = fmaf(w.y, h.y, a1);
          a2 = fmaf(w.z, h.z, a2); a3 = fmaf(w.w, h.w, a3);
          float4 g = sb4[r * 64 + lane]; float4 v = w3[(wid * 2 + 1) * 512 + r * 64 + lane];
          a0 = fmaf(v.x, g.x, a0); a1 = fmaf(v.y, g.y, a1);
          a2 = fmaf(v.z, g.z, a2); a3 = fmaf(v.w, g.w, a3);
        }
      }
      float acc = wred((a0 + a1) + (a2 + a3));

      if (lane == 0) {
        float pre = acc + bias[l];
        float h   = fmaxf(pre, 0.f);
        float bin = h / (h + 1e-12f);
        if (l < 3) {
          stf_dev(&hraw[(size_t)l * C + j], h);                    // critical
          stf_dev(&hidb[(size_t)((p ^ 1) * 4 + l) * C + j], bin);
        } else {
          stf_dev(&inp[(size_t)(p ^ 1) * C + j], bin);             // critical
          stf_dev(&hidb[(size_t)((p ^ 1) * 4 + 3) * C + j], bin);
          out[(size_t)t * C + j] = bin;
        }
      }
      // Release: hipcc drains vmcnt(0) before s_barrier, so all waves'
      // agent-scope write-through stores are globally visible when any
      // thread passes this barrier. Also protects sh_a/sh_b reuse.
      __syncthreads();
      if (tid == 0)
        __hip_atomic_store(&done[blockIdx.x], tgt + 1,
                           __ATOMIC_RELAXED, __HIP_MEMORY_SCOPE_AGENT);
    }
  }
}

extern "C" void kernel_launch(void* const* d_in, const int* in_sizes, int n_in,
                              void* d_out, int out_size, void* d_ws, size_t ws_size,
                              hipStream_t stream) {
  const float* x       = (const float*)d_in[0];
  const float* lp_w    = (const float*)d_in[1];
  const float* lp_b    = (const float*)d_in[2];
  const float* lp_wout = (const float*)d_in[3];
  const float* lp_bout = (const float*)d_in[4];
  const float* w_ih    = (const float*)d_in[5];
  const float* b_ih    = (const float*)d_in[6];
  const float* w_hh    = (const float*)d_in[7];
  const float* b_hh    = (const float*)d_in[8];
  float* out = (float*)d_out;
  u64*   ws  = (u64*)d_ws;

  hipLaunchKernelGGL(init_kernel, dim3(8), dim3(256), 0, stream, x, ws);
  hipLaunchKernelGGL(rnn_persist, dim3(NB), dim3(NT),
                     8 * 2 * 512 * sizeof(float4) /* 128 KB dyn LDS */, stream,
                     x, lp_w, lp_b, lp_wout, lp_bout,
                     w_ih, b_ih, w_hh, b_hh, out, ws);
}